// Round 9
// baseline (614.196 us; speedup 1.0000x reference)
//
#include <hip/hip_runtime.h>
#include <hip/hip_bf16.h>
#include <stdint.h>

#define T_ROWS 131072
#define GCNT   64
#define KDIM   1024
#define NDIM   512
#define BM     128
#define BN     128
#define BK     64
#define KTILES (KDIM / BK)     // 16
#define MT_MAX 1088            // upper bound on 128-row tiles (~1055 actual)
#define NBLK   (MT_MAX * 4)    // 4352 blocks, /8 = 544 (XCD swizzle exact)

typedef __attribute__((ext_vector_type(4))) float f32x4;
typedef __attribute__((ext_vector_type(8))) short s16x8;
typedef __attribute__((address_space(3))) unsigned int lds_u32;
typedef const __attribute__((address_space(1))) unsigned int gbl_u32;

static __device__ __forceinline__ short f2bf(float f) {
  __hip_bfloat16 h = __float2bfloat16(f);
  return __builtin_bit_cast(short, h);
}

// ---------------------------------------------------------------------------
// Pre-pass: b [G][K][N] fp32 -> bt: per (g, nt128, kt) 16KB bf16 tile images,
// layout [G][4][16][16384B]. Image byte for B[k][n] (k in [0,64), n in
// [0,128)):  n*128 + (((k>>3) ^ (n&7))<<4) + (k&7)*2   (bank swizzle baked).
// ---------------------------------------------------------------------------
__global__ __launch_bounds__(256) void bt_kernel(const float* __restrict__ b,
                                                 char* __restrict__ bt) {
  __shared__ short lt[64 * 130];
  int bid = blockIdx.x;               // g*64 + nt*16 + kt
  int kt = bid & 15, nt = (bid >> 4) & 3, g = bid >> 6;
  int t = threadIdx.x;
  const float* src = b + ((size_t)(g * KDIM + kt * BK)) * NDIM + nt * 128;
#pragma unroll
  for (int i = 0; i < 32; i++) {
    int idx = i * 256 + t;
    int kk = idx >> 7, nn = idx & 127;
    lt[kk * 130 + nn] = f2bf(src[(size_t)kk * NDIM + nn]);
  }
  __syncthreads();
  char* dst = bt + ((size_t)bid << 14);
#pragma unroll
  for (int j = 0; j < 4; j++) {
    int chunk = j * 256 + t;
    int n = chunk >> 3;
    int slot = (chunk & 7) ^ (n & 7);
    s16x8 v;
#pragma unroll
    for (int i = 0; i < 8; i++) v[i] = lt[(slot * 8 + i) * 130 + n];
    *(s16x8*)(dst + (size_t)chunk * 16) = v;
  }
}

// ---------------------------------------------------------------------------
// Grouped GEMM: 128x128 tile, 4 waves (2Mx2N), BK=64.
// A: global -> REGISTERS directly (16 dwordx4/wave/tile), cvt in-reg. No LDS.
// B: pre-swizzled bt image via global_load_lds, double-buffered 32 KB LDS.
// Per tile kt (unconditional for kt=0..14; kt=15 peeled):
//   stageB(kt+1 -> nxt)   [4 DMA, OLDEST this iter -- order pinned]
//   cvtAll: af8 = bf16(va)  [auto-waits counted vmcnt(4): A(kt) retired]
//   issueA(kt+1 -> va)    [16 loads, newest; fly across the barrier]
//   MFMA 32 (bf from LDS[cur], compiler-counted lgkm)
//   s_waitcnt vmcnt(16)   [retire B(kt+1) DMAs only]; s_barrier
// vmcnt never drains to 0 in the loop; zero ds_writes, zero lgkm at barrier.
// ---------------------------------------------------------------------------
__global__ __launch_bounds__(256, 2) void gemm2(
    const float* __restrict__ a, const char* __restrict__ bt,
    const int* __restrict__ sizes, const int* __restrict__ offs,
    float* __restrict__ out) {
  __shared__ __align__(16) char lds_b[2][BN * BK * 2];  // 2 x 16 KB

  int bid0 = blockIdx.x;
  int bid = (bid0 & 7) * (NBLK / 8) + (bid0 >> 3);  // XCD-chunked swizzle
  int bn = bid & 3;      // bn fastest: 4 blocks sharing an A panel adjacent
  int tm = bid >> 2;

  int g = -1, m_loc = 0, base = 0;
#pragma unroll
  for (int i = 0; i < GCNT; i++) {
    int tg = ((sizes[i] + 127) & ~127) >> 7;
    if (tm >= base && tm < base + tg) { g = i; m_loc = (tm - base) << 7; }
    base += tg;
  }
  if (g < 0) return;
  int size = sizes[g], off = offs[g], valid = size - m_loc;

  int t = threadIdx.x, lane = t & 63, wid = t >> 6;
  int wm = wid >> 1, wn = wid & 1, lr = lane & 15, q = lane >> 4;

  // A per-fragment byte offsets: row = off+m_loc+wm*64+fm*16+lr, k-chunk q
  int aq[4];
#pragma unroll
  for (int fm = 0; fm < 4; fm++) {
    int row = off + m_loc + wm * 64 + fm * 16 + lr;
    if (row >= T_ROWS) row = T_ROWS - 1;   // junk rows masked at store
    aq[fm] = row * (KDIM * 4) + q * 32;    // byte offset
  }
  const char* a8 = (const char*)a;

  const char* btimg = bt + ((size_t)((g << 6) + (bn << 4)) << 14);

  f32x4 acc[4][4];
#pragma unroll
  for (int i = 0; i < 4; i++)
#pragma unroll
    for (int j = 0; j < 4; j++) acc[i][j] = (f32x4){0.f, 0.f, 0.f, 0.f};

  f32x4 va[16];       // A(kt+1) fp32 bank: [fm][ks][h]
  s16x8 af8[4][2];    // A(kt) bf16 fragments [fm][ks]

  auto issueA = [&](int kt) {
#pragma unroll
    for (int fm = 0; fm < 4; fm++)
#pragma unroll
      for (int ks = 0; ks < 2; ks++)
#pragma unroll
        for (int h = 0; h < 2; h++)
          va[fm * 4 + ks * 2 + h] = *(const f32x4*)(
              a8 + aq[fm] + kt * (BK * 4) + ks * 128 + h * 16);
  };
  auto cvtAll = [&]() {  // consumes va (auto counted vmcnt), fills af8
#pragma unroll
    for (int fm = 0; fm < 4; fm++)
#pragma unroll
      for (int ks = 0; ks < 2; ks++) {
        s16x8 v;
#pragma unroll
        for (int h = 0; h < 2; h++)
#pragma unroll
          for (int e = 0; e < 4; e++)
            v[h * 4 + e] = f2bf(va[fm * 4 + ks * 2 + h][e]);
        af8[fm][ks] = v;
      }
  };
  auto stageB = [&](int kt, int c) {
#pragma unroll
    for (int i = 0; i < 4; i++) {
      int wc = wid * 4 + i;                 // wave-uniform 1KB chunk, 0..15
      int cc = wc * 64 + lane;
      const char* gsrc = btimg + ((size_t)kt << 14) + (size_t)cc * 16;
      __builtin_amdgcn_global_load_lds(
          (gbl_u32*)gsrc, (lds_u32*)((char*)lds_b[c] + wc * 1024), 16, 0, 0);
    }
  };
  auto computeMFMA = [&](int c) {
    s16x8 bf[2][4];
#pragma unroll
    for (int ks = 0; ks < 2; ks++)
#pragma unroll
      for (int fn = 0; fn < 4; fn++) {
        int n = wn * 64 + fn * 16 + lr;
        int slot = (ks * 4 + q) ^ (n & 7);
        bf[ks][fn] =
            *(const s16x8*)((const char*)lds_b[c] + n * 128 + slot * 16);
      }
    __builtin_amdgcn_s_setprio(1);
#pragma unroll
    for (int ks = 0; ks < 2; ks++)
#pragma unroll
      for (int fm = 0; fm < 4; fm++)
#pragma unroll
        for (int fn = 0; fn < 4; fn++)
          acc[fm][fn] = __builtin_amdgcn_mfma_f32_16x16x32_bf16(
              af8[fm][ks], bf[ks][fn], acc[fm][fn], 0, 0, 0);
    __builtin_amdgcn_s_setprio(0);
  };

  // prologue: B(0) DMA (oldest), A(0) loads (newer, fly across barrier)
  stageB(0, 0);
  __builtin_amdgcn_sched_barrier(0);
  issueA(0);
  asm volatile("s_waitcnt vmcnt(16)" ::: "memory");  // retire B(0) only
  __builtin_amdgcn_s_barrier();

  // main loop: fully unconditional
  for (int kt = 0; kt < KTILES - 1; kt++) {
    int cur = kt & 1, nxt = cur ^ 1;
    stageB(kt + 1, nxt);                   // 4 DMA, oldest this iter
    __builtin_amdgcn_sched_barrier(0);     // pin: B before A issues
    cvtAll();                              // auto vmcnt(4): waits A(kt)
    issueA(kt + 1);                        // 16 loads, newest
    computeMFMA(cur);
    asm volatile("s_waitcnt vmcnt(16)" ::: "memory");  // retire B(kt+1)
    __builtin_amdgcn_s_barrier();
  }
  // peeled kt = 15: no new issues; cvt auto-waits A(15), compute from LDS[1]
  cvtAll();
  computeMFMA(1);

  // epilogue: D frag col = lane&15, row = (lane>>4)*4 + j; masked rows
  size_t orow0 = (size_t)(off + m_loc);
#pragma unroll
  for (int fm = 0; fm < 4; fm++) {
#pragma unroll
    for (int j = 0; j < 4; j++) {
      int rm = wm * 64 + fm * 16 + q * 4 + j;
      if (rm < valid) {
        float* orow = out + (orow0 + rm) * NDIM + bn * BN + wn * 64 + lr;
#pragma unroll
        for (int fn = 0; fn < 4; fn++) orow[fn * 16] = acc[fm][fn][j];
      }
    }
  }
}

// ---------------------------------------------------------------------------
// Fallback (no workspace): B transposed in-kernel via LDS (round-8 style),
// A direct-to-register as above.
// ---------------------------------------------------------------------------
__global__ __launch_bounds__(256, 2) void gemm_fb(
    const float* __restrict__ a, const float* __restrict__ b,
    const int* __restrict__ sizes, const int* __restrict__ offs,
    float* __restrict__ out) {
  __shared__ __align__(16) char lds_b[2][BN * BK * 2];

  int bid0 = blockIdx.x;
  int bid = (bid0 & 7) * (NBLK / 8) + (bid0 >> 3);
  int bn = bid & 3;
  int tm = bid >> 2;

  int g = -1, m_loc = 0, base = 0;
#pragma unroll
  for (int i = 0; i < GCNT; i++) {
    int tg = ((sizes[i] + 127) & ~127) >> 7;
    if (tm >= base && tm < base + tg) { g = i; m_loc = (tm - base) << 7; }
    base += tg;
  }
  if (g < 0) return;
  int size = sizes[g], off = offs[g], valid = size - m_loc;

  int t = threadIdx.x, lane = t & 63, wid = t >> 6;
  int wm = wid >> 1, wn = wid & 1, lr = lane & 15, q = lane >> 4;

  int aq[4];
#pragma unroll
  for (int fm = 0; fm < 4; fm++) {
    int row = off + m_loc + wm * 64 + fm * 16 + lr;
    if (row >= T_ROWS) row = T_ROWS - 1;
    aq[fm] = row * (KDIM * 4) + q * 32;
  }
  const char* a8 = (const char*)a;
  int fb_n = t >> 1, fb_kh = (t & 1) * 32;

  f32x4 acc[4][4];
#pragma unroll
  for (int i = 0; i < 4; i++)
#pragma unroll
    for (int j = 0; j < 4; j++) acc[i][j] = (f32x4){0.f, 0.f, 0.f, 0.f};
  f32x4 va[16];
  s16x8 af8[4][2];

  auto issueA = [&](int kt) {
#pragma unroll
    for (int fm = 0; fm < 4; fm++)
#pragma unroll
      for (int ks = 0; ks < 2; ks++)
#pragma unroll
        for (int h = 0; h < 2; h++)
          va[fm * 4 + ks * 2 + h] = *(const f32x4*)(
              a8 + aq[fm] + kt * (BK * 4) + ks * 128 + h * 16);
  };
  auto cvtAll = [&]() {
#pragma unroll
    for (int fm = 0; fm < 4; fm++)
#pragma unroll
      for (int ks = 0; ks < 2; ks++) {
        s16x8 v;
#pragma unroll
        for (int h = 0; h < 2; h++)
#pragma unroll
          for (int e = 0; e < 4; e++)
            v[h * 4 + e] = f2bf(va[fm * 4 + ks * 2 + h][e]);
        af8[fm][ks] = v;
      }
  };
  auto stageB = [&](int kt, int c) {
    const float* p = b + (size_t)g * KDIM * NDIM +
                     (size_t)(kt * BK + fb_kh) * NDIM + bn * BN + fb_n;
    float vals[32];
#pragma unroll
    for (int i = 0; i < 32; i++) vals[i] = p[(size_t)i * NDIM];
    char* lb = (char*)lds_b[c] + fb_n * 128;
#pragma unroll
    for (int i8 = 0; i8 < 4; i8++) {
      int slot = (fb_kh >> 3) + i8;
      s16x8 v;
#pragma unroll
      for (int e = 0; e < 8; e++) v[e] = f2bf(vals[i8 * 8 + e]);
      *(s16x8*)(lb + ((slot ^ (fb_n & 7)) << 4)) = v;
    }
  };
  auto computeMFMA = [&](int c) {
    s16x8 bf[2][4];
#pragma unroll
    for (int ks = 0; ks < 2; ks++)
#pragma unroll
      for (int fn = 0; fn < 4; fn++) {
        int n = wn * 64 + fn * 16 + lr;
        int slot = (ks * 4 + q) ^ (n & 7);
        bf[ks][fn] =
            *(const s16x8*)((const char*)lds_b[c] + n * 128 + slot * 16);
      }
#pragma unroll
    for (int ks = 0; ks < 2; ks++)
#pragma unroll
      for (int fm = 0; fm < 4; fm++)
#pragma unroll
        for (int fn = 0; fn < 4; fn++)
          acc[fm][fn] = __builtin_amdgcn_mfma_f32_16x16x32_bf16(
              af8[fm][ks], bf[ks][fn], acc[fm][fn], 0, 0, 0);
  };

  issueA(0);
  stageB(0, 0);
  __syncthreads();
  for (int kt = 0; kt < KTILES; kt++) {
    int cur = kt & 1, nxt = cur ^ 1;
    bool more = (kt + 1 < KTILES);
    cvtAll();
    if (more) issueA(kt + 1);
    computeMFMA(cur);
    if (more) {
      stageB(kt + 1, nxt);
      __syncthreads();
    }
  }

  size_t orow0 = (size_t)(off + m_loc);
#pragma unroll
  for (int fm = 0; fm < 4; fm++) {
#pragma unroll
    for (int j = 0; j < 4; j++) {
      int rm = wm * 64 + fm * 16 + q * 4 + j;
      if (rm < valid) {
        float* orow = out + (orow0 + rm) * NDIM + bn * BN + wn * 64 + lr;
#pragma unroll
        for (int fn = 0; fn < 4; fn++) orow[fn * 16] = acc[fm][fn][j];
      }
    }
  }
}

extern "C" void kernel_launch(void* const* d_in, const int* in_sizes, int n_in,
                              void* d_out, int out_size, void* d_ws,
                              size_t ws_size, hipStream_t stream) {
  const float* a = (const float*)d_in[0];
  const float* b = (const float*)d_in[1];
  const int* sizes = (const int*)d_in[2];
  const int* offs = (const int*)d_in[3];
  float* out = (float*)d_out;

  const size_t bt_bytes = (size_t)GCNT * KDIM * NDIM * 2;  // 64 MB
  if (ws_size >= bt_bytes) {
    bt_kernel<<<GCNT * 64, 256, 0, stream>>>(b, (char*)d_ws);
    gemm2<<<NBLK, 256, 0, stream>>>(a, (const char*)d_ws, sizes, offs, out);
  } else {
    gemm_fb<<<NBLK, 256, 0, stream>>>(a, b, sizes, offs, out);
  }
}

// Round 10
// 325.110 us; speedup vs baseline: 1.8892x; 1.8892x over previous
//
#include <hip/hip_runtime.h>
#include <hip/hip_bf16.h>
#include <stdint.h>

#define T_ROWS 131072
#define GCNT   64
#define KDIM   1024
#define NDIM   512
#define BM     256
#define BN     256
#define BK     64
#define KTILES (KDIM / BK)     // 16
#define MT_MAX 640             // upper bound on 256-row tiles (actual ~550)
#define NBLK   (MT_MAX * 2)    // 1280 blocks, /8 = 160 (XCD swizzle exact)

typedef __attribute__((ext_vector_type(4))) float f32x4;
typedef __attribute__((ext_vector_type(8))) short s16x8;
typedef __attribute__((ext_vector_type(4))) short s16x4;
typedef __attribute__((address_space(3))) unsigned int lds_u32;
typedef const __attribute__((address_space(1))) unsigned int gbl_u32;

static __device__ __forceinline__ short f2bf(float f) {
  __hip_bfloat16 h = __float2bfloat16(f);
  return __builtin_bit_cast(short, h);
}

// ---------------------------------------------------------------------------
// Pre-pass: b [G][K][N] fp32 -> bt: per (g, nt128, kt) 16KB bf16 tile images,
// layout [G][4][16][16384B]. Image byte for B[k][n] (k in [0,64), n in
// [0,128)):  n*128 + (((k>>3) ^ (n&7))<<4) + (k&7)*2   (bank swizzle baked).
// ---------------------------------------------------------------------------
__global__ __launch_bounds__(256) void bt_kernel(const float* __restrict__ b,
                                                 char* __restrict__ bt) {
  __shared__ short lt[64 * 130];
  int bid = blockIdx.x;               // g*64 + nt*16 + kt
  int kt = bid & 15, nt = (bid >> 4) & 3, g = bid >> 6;
  int t = threadIdx.x;
  const float* src = b + ((size_t)(g * KDIM + kt * BK)) * NDIM + nt * 128;
#pragma unroll
  for (int i = 0; i < 32; i++) {
    int idx = i * 256 + t;
    int kk = idx >> 7, nn = idx & 127;
    lt[kk * 130 + nn] = f2bf(src[(size_t)kk * NDIM + nn]);
  }
  __syncthreads();
  char* dst = bt + ((size_t)bid << 14);
#pragma unroll
  for (int j = 0; j < 4; j++) {
    int chunk = j * 256 + t;
    int n = chunk >> 3;
    int slot = (chunk & 7) ^ (n & 7);
    s16x8 v;
#pragma unroll
    for (int i = 0; i < 8; i++) v[i] = lt[(slot * 8 + i) * 130 + n];
    *(s16x8*)(dst + (size_t)chunk * 16) = v;
  }
}

// ---------------------------------------------------------------------------
// 8-phase grouped GEMM, 256x256, 8 waves (2Mx4N), BK=64, 128KB LDS.
// Per tile kt (cur=kt&1, nxt=cur^1); B issued FIRST, A issued LAST so the
// boundary vmcnt(8) retires exactly B(kt+1) (in-order retirement):
//  P1: dsA(h0,ks0)+dsB(ks0) | B-DMA(kt+1->nxt,h0) | bar lgkm0 16MFMA bar
//  P2: dsA(h0,ks1)+dsB(ks1) | B-DMA(kt+1->nxt,h1) | bar lgkm0 16MFMA bar
//  P3: dsA(h1,ks0) | cvt+write A(kt+1,h0->nxt) [auto vmcnt(8), counted],
//                    issueA(kt+2,h0) into recycled bank | bar lgkm0 MFMA bar
//  P4: dsA(h1,ks1) | cvt+write A(kt+1,h1->nxt), issueA(kt+2,h1)
//      | boundary: s_waitcnt vmcnt(8) lgkmcnt(0) [retire B(kt+1); keep
//        A(kt+2)'s 8 loads flying] ; s_barrier
// vmcnt NEVER drains to 0 in the main loop (kt=0..13 unconditional).
// ---------------------------------------------------------------------------
__global__ __launch_bounds__(512, 2) void gemm8(
    const float* __restrict__ a, const char* __restrict__ bt,
    const int* __restrict__ sizes, const int* __restrict__ offs,
    float* __restrict__ out) {
  __shared__ __align__(16) short lds_a[2][BM * BK];     // 2 x 32 KB
  __shared__ __align__(16) char lds_b[2][BN * BK * 2];  // 2 x 32 KB

  int bid0 = blockIdx.x;
  int bid = (bid0 & 7) * (NBLK / 8) + (bid0 >> 3);  // XCD-chunked swizzle
  int bn = bid & 1;                                 // A-sharing pair adjacent
  int tm = bid >> 1;

  int g = -1, m_loc = 0, base = 0;
#pragma unroll
  for (int i = 0; i < GCNT; i++) {
    int ps = (sizes[i] + 127) & ~127;
    int tg = (ps + 255) >> 8;
    if (tm >= base && tm < base + tg) { g = i; m_loc = (tm - base) << 8; }
    base += tg;
  }
  if (g < 0) return;
  int size = sizes[g], off = offs[g], valid = size - m_loc;

  int t = threadIdx.x, lane = t & 63, wid = t >> 6;
  int wm = wid >> 2, wn = wid & 3, lr = lane & 15, q = lane >> 4;

  // A staging: half h covers rows h*128..h*128+127. Thread t owns rows
  // h*128 + {0,32,64,96} + (t>>4), 16B fp32 chunk (t&15) of each row.
  int r0 = t >> 4, c16 = t & 15;
  int aoff[2][4];
#pragma unroll
  for (int h = 0; h < 2; h++)
#pragma unroll
    for (int i = 0; i < 4; i++) {
      int row = off + m_loc + h * 128 + i * 32 + r0;
      if (row >= T_ROWS) row = T_ROWS - 1;  // junk rows masked at store
      aoff[h][i] = row * KDIM + c16 * 4;
    }
  // LDS write byte within half-region: tile row = h*128 + i*32 + r0;
  // (row&7)==(r0&7) since h*128, i*32 are multiples of 8.
  int a_wbyte = r0 * 128 + (((c16 >> 1) ^ (r0 & 7)) << 4) + (c16 & 1) * 8;

  const char* btbase = bt + ((size_t)g << 20);

  f32x4 acc[8][4];
#pragma unroll
  for (int i = 0; i < 8; i++)
#pragma unroll
    for (int j = 0; j < 4; j++) acc[i][j] = (f32x4){0.f, 0.f, 0.f, 0.f};
  f32x4 va[2][4];     // recycled A fp32 bank, per half
  s16x8 af[4], bf0[4], bf1[4];

  auto issueA = [&](int kt, int h) {
#pragma unroll
    for (int i = 0; i < 4; i++)
      va[h][i] = *(const f32x4*)(a + aoff[h][i] + kt * BK);
  };
  auto commitA = [&](int c, int h) {  // cvt auto-waits counted vmcnt on va[h]
    char* db = (char*)lds_a[c] + h * 16384 + a_wbyte;
#pragma unroll
    for (int i = 0; i < 4; i++) {
      s16x4 v;
#pragma unroll
      for (int e = 0; e < 4; e++) v[e] = f2bf(va[h][i][e]);
      *(s16x4*)(db + i * 4096) = v;   // rows step 32 -> 32*128 bytes
    }
  };
  auto issueB = [&](int kt, int c, int h) {
#pragma unroll
    for (int i = 0; i < 2; i++) {
      int wc = wid * 4 + h * 2 + i;          // wave-uniform chunk id
      int sub = wc >> 4;
      int cc = (wc & 15) * 64 + lane;
      const char* gsrc =
          btbase + (((size_t)((bn * 2 + sub) * 16 + kt)) << 14) + cc * 16;
      __builtin_amdgcn_global_load_lds(
          (gbl_u32*)gsrc, (lds_u32*)((char*)lds_b[c] + wc * 1024), 16, 0, 0);
    }
  };
  auto dsA = [&](int c, int half, int ks) {
#pragma unroll
    for (int i = 0; i < 4; i++) {
      int row = wm * 128 + (half * 4 + i) * 16 + lr;
      int slot = (ks * 4 + q) ^ (row & 7);
      af[i] = *(const s16x8*)((const char*)lds_a[c] + row * 128 + slot * 16);
    }
  };
  auto dsB = [&](int c, int ks, s16x8* bf) {
#pragma unroll
    for (int fn = 0; fn < 4; fn++) {
      int n = wn * 64 + fn * 16 + lr;
      int slot = (ks * 4 + q) ^ (n & 7);
      bf[fn] = *(const s16x8*)((const char*)lds_b[c] + (n >> 7) * 16384 +
                               (n & 127) * 128 + slot * 16);
    }
  };
  auto pbar = [&]() {
    __builtin_amdgcn_sched_barrier(0);
    __builtin_amdgcn_s_barrier();
    asm volatile("s_waitcnt lgkmcnt(0)" ::: "memory");
    __builtin_amdgcn_sched_barrier(0);
  };
  auto mfmaQ = [&](const s16x8* bf, int fmb) {
    __builtin_amdgcn_s_setprio(1);
#pragma unroll
    for (int fm = 0; fm < 4; fm++)
#pragma unroll
      for (int fn = 0; fn < 4; fn++)
        acc[fmb + fm][fn] = __builtin_amdgcn_mfma_f32_16x16x32_bf16(
            af[fm], bf[fn], acc[fmb + fm][fn], 0, 0, 0);
    __builtin_amdgcn_s_setprio(0);
    __builtin_amdgcn_sched_barrier(0);
  };

  // prologue: B(0)->buf0 (oldest); A(0)->bank->cvt->buf0 (drains, once);
  // A(1)->bank (8 loads, newest, fly across the barrier).
  issueB(0, 0, 0);
  issueB(0, 0, 1);
  issueA(0, 0);
  issueA(0, 1);
  commitA(0, 0);        // auto-wait drains va (and thus B(0) per in-order)
  commitA(0, 1);
  issueA(1, 0);
  issueA(1, 1);
  asm volatile("s_waitcnt vmcnt(8) lgkmcnt(0)" ::: "memory");
  __builtin_amdgcn_sched_barrier(0);
  __builtin_amdgcn_s_barrier();

  // main loop kt = 0..13, fully unconditional
  for (int kt = 0; kt < KTILES - 2; kt++) {
    int cur = kt & 1, nxt = cur ^ 1;
    // P1
    dsA(cur, 0, 0);
    dsB(cur, 0, bf0);
    issueB(kt + 1, nxt, 0);       // B first: oldest in this tile
    pbar();
    mfmaQ(bf0, 0);
    __builtin_amdgcn_s_barrier();
    // P2
    dsA(cur, 0, 1);
    dsB(cur, 1, bf1);
    issueB(kt + 1, nxt, 1);
    pbar();
    mfmaQ(bf1, 0);
    __builtin_amdgcn_s_barrier();
    // P3
    dsA(cur, 1, 0);
    commitA(nxt, 0);              // cvt auto vmcnt(8): waits A(kt+1) h0
    issueA(kt + 2, 0);            // recycled bank, newest
    pbar();
    mfmaQ(bf0, 4);
    __builtin_amdgcn_s_barrier();
    // P4
    dsA(cur, 1, 1);
    commitA(nxt, 1);
    issueA(kt + 2, 1);
    __builtin_amdgcn_sched_barrier(0);
    // boundary: retire B(kt+1) (4 oldest), keep A(kt+2) (8) in flight
    asm volatile("s_waitcnt vmcnt(8) lgkmcnt(0)" ::: "memory");
    __builtin_amdgcn_sched_barrier(0);
    __builtin_amdgcn_s_barrier();
    mfmaQ(bf1, 4);
    __builtin_amdgcn_s_barrier();
  }

  // peeled kt = 14 (cur=0, nxt=1): stage B(15); commit A(15); no issueA(16)
  {
    dsA(0, 0, 0); dsB(0, 0, bf0); issueB(15, 1, 0);
    pbar(); mfmaQ(bf0, 0); __builtin_amdgcn_s_barrier();
    dsA(0, 0, 1); dsB(0, 1, bf1); issueB(15, 1, 1);
    pbar(); mfmaQ(bf1, 0); __builtin_amdgcn_s_barrier();
    dsA(0, 1, 0); commitA(1, 0);
    pbar(); mfmaQ(bf0, 4); __builtin_amdgcn_s_barrier();
    dsA(0, 1, 1); commitA(1, 1);
    asm volatile("s_waitcnt vmcnt(0) lgkmcnt(0)" ::: "memory");
    __builtin_amdgcn_sched_barrier(0);
    __builtin_amdgcn_s_barrier();
    mfmaQ(bf1, 4);
    __builtin_amdgcn_s_barrier();
  }
  // peeled kt = 15 (cur=1): compute only
  {
    dsA(1, 0, 0); dsB(1, 0, bf0); pbar(); mfmaQ(bf0, 0);
    __builtin_amdgcn_s_barrier();
    dsA(1, 0, 1); dsB(1, 1, bf1); pbar(); mfmaQ(bf1, 0);
    __builtin_amdgcn_s_barrier();
    dsA(1, 1, 0); pbar(); mfmaQ(bf0, 4);
    __builtin_amdgcn_s_barrier();
    dsA(1, 1, 1); pbar(); mfmaQ(bf1, 4);
  }

  // epilogue: D frag col = lane&15, row = (lane>>4)*4 + j; masked rows
  size_t orow0 = (size_t)(off + m_loc);
#pragma unroll
  for (int fm = 0; fm < 8; fm++) {
#pragma unroll
    for (int j = 0; j < 4; j++) {
      int rm = wm * 128 + fm * 16 + q * 4 + j;
      if (rm < valid) {
        float* orow = out + (orow0 + rm) * NDIM + bn * BN + wn * 64 + lr;
#pragma unroll
        for (int fn = 0; fn < 4; fn++) orow[fn * 16] = acc[fm][fn][j];
      }
    }
  }
}

// ---------------------------------------------------------------------------
// Fallback (no workspace): round-2 2-phase kernel, B transposed in-kernel.
// ---------------------------------------------------------------------------
__global__ __launch_bounds__(512, 2) void gemm_fb(
    const float* __restrict__ a, const float* __restrict__ b,
    const int* __restrict__ sizes, const int* __restrict__ offs,
    float* __restrict__ out) {
  __shared__ __align__(16) short lds_a[2][BM * BK];
  __shared__ __align__(16) char lds_b[2][BN * BK * 2];

  int bid0 = blockIdx.x;
  int bid = (bid0 & 7) * (NBLK / 8) + (bid0 >> 3);
  int bn = bid & 1;
  int tm = bid >> 1;

  int g = -1, m_loc = 0, base = 0;
#pragma unroll
  for (int i = 0; i < GCNT; i++) {
    int ps = (sizes[i] + 127) & ~127;
    int tg = (ps + 255) >> 8;
    if (tm >= base && tm < base + tg) { g = i; m_loc = (tm - base) << 8; }
    base += tg;
  }
  if (g < 0) return;
  int size = sizes[g], off = offs[g], valid = size - m_loc;

  int t = threadIdx.x, lane = t & 63, wid = t >> 6;
  int wm = wid >> 2, wn = wid & 3, lr = lane & 15, q = lane >> 4;

  int r0 = t >> 4, c16 = t & 15;
  int aoff[8];
#pragma unroll
  for (int i = 0; i < 8; i++) {
    int row = off + m_loc + i * 32 + r0;
    if (row >= T_ROWS) row = T_ROWS - 1;
    aoff[i] = row * KDIM + c16 * 4;
  }
  int a_wbyte = r0 * 128 + (((c16 >> 1) ^ (r0 & 7)) << 4) + (c16 & 1) * 8;
  int fb_n = t >> 1, fb_kh = (t & 1) * 32;

  f32x4 acc[8][4];
#pragma unroll
  for (int i = 0; i < 8; i++)
#pragma unroll
    for (int j = 0; j < 4; j++) acc[i][j] = (f32x4){0.f, 0.f, 0.f, 0.f};
  f32x4 va[8];

  auto loadA = [&](int kt) {
#pragma unroll
    for (int i = 0; i < 8; i++) va[i] = *(const f32x4*)(a + aoff[i] + kt * BK);
  };
  auto writeA = [&](int c) {
    char* db = (char*)lds_a[c] + a_wbyte;
#pragma unroll
    for (int i = 0; i < 8; i++) {
      s16x4 v;
#pragma unroll
      for (int e = 0; e < 4; e++) v[e] = f2bf(va[i][e]);
      *(s16x4*)(db + i * 4096) = v;
    }
  };
  auto stageB = [&](int kt, int c) {
    const float* p = b + (size_t)g * KDIM * NDIM +
                     (size_t)(kt * BK + fb_kh) * NDIM + bn * BN + fb_n;
    float vals[32];
#pragma unroll
    for (int i = 0; i < 32; i++) vals[i] = p[(size_t)i * NDIM];
    int nn = fb_n & 127;
    char* lb = (char*)lds_b[c] + (fb_n >> 7) * 16384 + nn * 128;
#pragma unroll
    for (int i8 = 0; i8 < 4; i8++) {
      int slot = (fb_kh >> 3) + i8;
      s16x8 v;
#pragma unroll
      for (int e = 0; e < 8; e++) v[e] = f2bf(vals[i8 * 8 + e]);
      *(s16x8*)(lb + (((slot ^ (nn & 7))) << 4)) = v;
    }
  };
  auto compute = [&](int c) {
#pragma unroll
    for (int ks = 0; ks < 2; ks++) {
      s16x8 af[8], bfr[4];
#pragma unroll
      for (int fm = 0; fm < 8; fm++) {
        int row = wm * 128 + fm * 16 + lr;
        int slot = (ks * 4 + q) ^ (row & 7);
        af[fm] = *(const s16x8*)((const char*)lds_a[c] + row * 128 + slot * 16);
      }
#pragma unroll
      for (int fn = 0; fn < 4; fn++) {
        int n = wn * 64 + fn * 16 + lr;
        int slot = (ks * 4 + q) ^ (n & 7);
        bfr[fn] = *(const s16x8*)((const char*)lds_b[c] + (n >> 7) * 16384 +
                                  (n & 127) * 128 + slot * 16);
      }
#pragma unroll
      for (int fm = 0; fm < 8; fm++)
#pragma unroll
        for (int fn = 0; fn < 4; fn++)
          acc[fm][fn] = __builtin_amdgcn_mfma_f32_16x16x32_bf16(
              af[fm], bfr[fn], acc[fm][fn], 0, 0, 0);
    }
  };

  loadA(0);
  stageB(0, 0);
  writeA(0);
  __syncthreads();
  int cur = 0;
  for (int kt = 0; kt < KTILES; kt++) {
    if (kt + 1 < KTILES) loadA(kt + 1);
    compute(cur);
    if (kt + 1 < KTILES) {
      stageB(kt + 1, cur ^ 1);
      writeA(cur ^ 1);
      __syncthreads();
      cur ^= 1;
    }
  }
  size_t orow0 = (size_t)(off + m_loc);
#pragma unroll
  for (int fm = 0; fm < 8; fm++) {
#pragma unroll
    for (int j = 0; j < 4; j++) {
      int rm = wm * 128 + fm * 16 + q * 4 + j;
      if (rm < valid) {
        float* orow = out + (orow0 + rm) * NDIM + bn * BN + wn * 64 + lr;
#pragma unroll
        for (int fn = 0; fn < 4; fn++) orow[fn * 16] = acc[fm][fn][j];
      }
    }
  }
}

extern "C" void kernel_launch(void* const* d_in, const int* in_sizes, int n_in,
                              void* d_out, int out_size, void* d_ws,
                              size_t ws_size, hipStream_t stream) {
  const float* a = (const float*)d_in[0];
  const float* b = (const float*)d_in[1];
  const int* sizes = (const int*)d_in[2];
  const int* offs = (const int*)d_in[3];
  float* out = (float*)d_out;

  const size_t bt_bytes = (size_t)GCNT * KDIM * NDIM * 2;  // 64 MB
  if (ws_size >= bt_bytes) {
    bt_kernel<<<GCNT * 64, 256, 0, stream>>>(b, (char*)d_ws);
    gemm8<<<NBLK, 512, 0, stream>>>(a, (const char*)d_ws, sizes, offs, out);
  } else {
    gemm_fb<<<NBLK, 512, 0, stream>>>(a, b, sizes, offs, out);
  }
}

// Round 11
// 289.809 us; speedup vs baseline: 2.1193x; 1.1218x over previous
//
#include <hip/hip_runtime.h>
#include <hip/hip_bf16.h>
#include <stdint.h>

#define T_ROWS 131072
#define GCNT   64
#define KDIM   1024
#define NDIM   512
#define BM     128
#define BN     128
#define BK     64
#define KTILES (KDIM / BK)     // 16
#define MT_MAX 1088            // upper bound on 128-row tiles (~1055 actual)
#define NBLK   (MT_MAX * 4)    // 4352 blocks, /8 = 544 (XCD swizzle exact)

typedef __attribute__((ext_vector_type(4))) float f32x4;
typedef __attribute__((ext_vector_type(8))) short s16x8;
typedef __attribute__((ext_vector_type(4))) short s16x4;
typedef __attribute__((address_space(3))) unsigned int lds_u32;
typedef const __attribute__((address_space(1))) unsigned int gbl_u32;

static __device__ __forceinline__ short f2bf(float f) {
  __hip_bfloat16 h = __float2bfloat16(f);
  return __builtin_bit_cast(short, h);
}

// ---------------------------------------------------------------------------
// Pre-pass: b [G][K][N] fp32 -> bt: per (g, nt128, kt) 16KB bf16 tile images,
// layout [G][4][16][16384B]. Image byte for B[k][n] (k in [0,64), n in
// [0,128)):  n*128 + (((k>>3) ^ (n&7))<<4) + (k&7)*2   (bank swizzle baked).
// ---------------------------------------------------------------------------
__global__ __launch_bounds__(256) void bt_kernel(const float* __restrict__ b,
                                                 char* __restrict__ bt) {
  __shared__ short lt[64 * 130];
  int bid = blockIdx.x;               // g*64 + nt*16 + kt
  int kt = bid & 15, nt = (bid >> 4) & 3, g = bid >> 6;
  int t = threadIdx.x;
  const float* src = b + ((size_t)(g * KDIM + kt * BK)) * NDIM + nt * 128;
#pragma unroll
  for (int i = 0; i < 32; i++) {
    int idx = i * 256 + t;
    int kk = idx >> 7, nn = idx & 127;
    lt[kk * 130 + nn] = f2bf(src[(size_t)kk * NDIM + nn]);
  }
  __syncthreads();
  char* dst = bt + ((size_t)bid << 14);
#pragma unroll
  for (int j = 0; j < 4; j++) {
    int chunk = j * 256 + t;
    int n = chunk >> 3;
    int slot = (chunk & 7) ^ (n & 7);
    s16x8 v;
#pragma unroll
    for (int i = 0; i < 8; i++) v[i] = lt[(slot * 8 + i) * 130 + n];
    *(s16x8*)(dst + (size_t)chunk * 16) = v;
  }
}

// ---------------------------------------------------------------------------
// m97-regime grouped GEMM: 128x128, 4 waves, BK=64, 48KB LDS -> 3 blocks/CU
// (12 waves/CU): cross-block TLP hides each block's serial chain.
// A: single-buffered 16KB (end-of-tile barrier protects overwrite).
// B: double-buffered 2x16KB via global_load_lds from pre-swizzled bt.
// Per tile kt (uniform for kt=0..14; kt=15 peeled):
//   stageB(kt+1 -> nxt)    [4 DMA]
//   writeA(kt)             [cvt auto-waits COUNTED vmcnt(4): retires
//                           A(kt) + the older B(kt); B(kt+1) keeps flying]
//   loadA(kt+1)            [8 fp32x4, fly across compute]
//   lgkmcnt(0); barrier    [publish ds_writes; B(kt) already retired]
//   compute(cur); barrier  [end-bar: frees lds_a + lds_b[nxt] for next tile]
// NO explicit vmcnt anywhere in the loop; vmcnt never drains below the
// 12 in-flight next-tile ops.
// ---------------------------------------------------------------------------
__global__ __launch_bounds__(256, 3) void gemm3(
    const float* __restrict__ a, const char* __restrict__ bt,
    const int* __restrict__ sizes, const int* __restrict__ offs,
    float* __restrict__ out) {
  __shared__ __align__(16) short lds_a[BM * BK];        // 16 KB, single
  __shared__ __align__(16) char lds_b[2][BN * BK * 2];  // 2 x 16 KB

  int bid0 = blockIdx.x;
  int bid = (bid0 & 7) * (NBLK / 8) + (bid0 >> 3);  // XCD-chunked swizzle
  int bn = bid & 3;      // bn fastest: 4 blocks sharing an A panel adjacent
  int tm = bid >> 2;

  int g = -1, m_loc = 0, base = 0;
#pragma unroll
  for (int i = 0; i < GCNT; i++) {
    int tg = ((sizes[i] + 127) & ~127) >> 7;
    if (tm >= base && tm < base + tg) { g = i; m_loc = (tm - base) << 7; }
    base += tg;
  }
  if (g < 0) return;
  int size = sizes[g], off = offs[g], valid = size - m_loc;

  int t = threadIdx.x, lane = t & 63, wid = t >> 6;
  int wm = wid >> 1, wn = wid & 1, lr = lane & 15, q = lane >> 4;

  // A staging: thread t owns rows i*16 + (t>>4), 16B fp32 chunk (t&15)
  int r0 = t >> 4, c16 = t & 15;
  int aoff[8];
#pragma unroll
  for (int i = 0; i < 8; i++) {
    int row = off + m_loc + i * 16 + r0;
    if (row >= T_ROWS) row = T_ROWS - 1;  // junk rows masked at store
    aoff[i] = row * KDIM + c16 * 4;
  }
  int a_wbyte = r0 * 128 + (((c16 >> 1) ^ (r0 & 7)) << 4) + (c16 & 1) * 8;

  const char* btimg = bt + ((size_t)((g << 6) + (bn << 4)) << 14);

  f32x4 acc[4][4];
#pragma unroll
  for (int i = 0; i < 4; i++)
#pragma unroll
    for (int j = 0; j < 4; j++) acc[i][j] = (f32x4){0.f, 0.f, 0.f, 0.f};
  f32x4 va[8];   // single recycled A fp32 bank

  auto loadA = [&](int kt) {
#pragma unroll
    for (int i = 0; i < 8; i++)
      va[i] = *(const f32x4*)(a + aoff[i] + kt * BK);
  };
  auto writeA = [&]() {  // cvt auto-waits counted vmcnt on va
    char* db = (char*)lds_a + a_wbyte;
#pragma unroll
    for (int i = 0; i < 8; i++) {
      s16x4 v;
#pragma unroll
      for (int e = 0; e < 4; e++) v[e] = f2bf(va[i][e]);
      *(s16x4*)(db + i * 2048) = v;   // row step 16 -> 16*128 bytes
    }
  };
  auto stageB = [&](int kt, int c) {
#pragma unroll
    for (int i = 0; i < 4; i++) {
      int wc = wid * 4 + i;                 // wave-uniform 1KB chunk, 0..15
      int cc = wc * 64 + lane;
      const char* gsrc = btimg + ((size_t)kt << 14) + (size_t)cc * 16;
      __builtin_amdgcn_global_load_lds(
          (gbl_u32*)gsrc, (lds_u32*)((char*)lds_b[c] + wc * 1024), 16, 0, 0);
    }
  };
  auto compute = [&](int c) {
#pragma unroll
    for (int ks = 0; ks < 2; ks++) {
      s16x8 af[4], bf[4];
#pragma unroll
      for (int fm = 0; fm < 4; fm++) {
        int row = wm * 64 + fm * 16 + lr;
        int slot = (ks * 4 + q) ^ (row & 7);
        af[fm] = *(const s16x8*)((const char*)lds_a + row * 128 + slot * 16);
      }
#pragma unroll
      for (int fn = 0; fn < 4; fn++) {
        int n = wn * 64 + fn * 16 + lr;
        int slot = (ks * 4 + q) ^ (n & 7);
        bf[fn] = *(const s16x8*)((const char*)lds_b[c] + n * 128 + slot * 16);
      }
      __builtin_amdgcn_s_setprio(1);
#pragma unroll
      for (int fm = 0; fm < 4; fm++)
#pragma unroll
        for (int fn = 0; fn < 4; fn++)
          acc[fm][fn] = __builtin_amdgcn_mfma_f32_16x16x32_bf16(
              af[fm], bf[fn], acc[fm][fn], 0, 0, 0);
      __builtin_amdgcn_s_setprio(0);
    }
  };

  // prologue: B(0) DMA first (oldest), then A(0) loads
  stageB(0, 0);
  __builtin_amdgcn_sched_barrier(0);
  loadA(0);

  // uniform loop kt = 0..14
  for (int kt = 0; kt < KTILES - 1; kt++) {
    int cur = kt & 1, nxt = cur ^ 1;
    stageB(kt + 1, nxt);                 // 4 DMA into the dead B buffer
    __builtin_amdgcn_sched_barrier(0);
    writeA();                            // cvt: counted vmcnt(4) -> retires
                                         // A(kt) AND the older B(kt)
    loadA(kt + 1);                       // 8 loads, fly across compute
    asm volatile("s_waitcnt lgkmcnt(0)" ::: "memory");
    __builtin_amdgcn_sched_barrier(0);
    __builtin_amdgcn_s_barrier();        // publish lds_a + B(kt) ready
    compute(cur);
    __builtin_amdgcn_sched_barrier(0);
    __builtin_amdgcn_s_barrier();        // end-bar: frees lds_a, lds_b[nxt]
  }
  // peeled kt = 15: cvt auto-drains (retires B(15) too), compute buf 1
  writeA();
  asm volatile("s_waitcnt lgkmcnt(0)" ::: "memory");
  __builtin_amdgcn_sched_barrier(0);
  __builtin_amdgcn_s_barrier();
  compute(1);

  // epilogue: D frag col = lane&15, row = (lane>>4)*4 + j; masked rows
  size_t orow0 = (size_t)(off + m_loc);
#pragma unroll
  for (int fm = 0; fm < 4; fm++) {
#pragma unroll
    for (int j = 0; j < 4; j++) {
      int rm = wm * 64 + fm * 16 + q * 4 + j;
      if (rm < valid) {
        float* orow = out + (orow0 + rm) * NDIM + bn * BN + wn * 64 + lr;
#pragma unroll
        for (int fn = 0; fn < 4; fn++) orow[fn * 16] = acc[fm][fn][j];
      }
    }
  }
}

// ---------------------------------------------------------------------------
// Fallback (no workspace): 2-phase kernel, B transposed in-kernel (r8 form).
// ---------------------------------------------------------------------------
__global__ __launch_bounds__(256, 2) void gemm_fb(
    const float* __restrict__ a, const float* __restrict__ b,
    const int* __restrict__ sizes, const int* __restrict__ offs,
    float* __restrict__ out) {
  __shared__ __align__(16) short lds_a2[2][BM * BK];
  __shared__ __align__(16) char lds_b2[2][BN * BK * 2];

  int bid0 = blockIdx.x;
  int bid = (bid0 & 7) * (NBLK / 8) + (bid0 >> 3);
  int bn = bid & 3;
  int tm = bid >> 2;

  int g = -1, m_loc = 0, base = 0;
#pragma unroll
  for (int i = 0; i < GCNT; i++) {
    int tg = ((sizes[i] + 127) & ~127) >> 7;
    if (tm >= base && tm < base + tg) { g = i; m_loc = (tm - base) << 7; }
    base += tg;
  }
  if (g < 0) return;
  int size = sizes[g], off = offs[g], valid = size - m_loc;

  int t = threadIdx.x, lane = t & 63, wid = t >> 6;
  int wm = wid >> 1, wn = wid & 1, lr = lane & 15, q = lane >> 4;

  int r0 = t >> 4, c16 = t & 15;
  int aoff[8];
#pragma unroll
  for (int i = 0; i < 8; i++) {
    int row = off + m_loc + i * 16 + r0;
    if (row >= T_ROWS) row = T_ROWS - 1;
    aoff[i] = row * KDIM + c16 * 4;
  }
  int a_wbyte = r0 * 128 + (((c16 >> 1) ^ (r0 & 7)) << 4) + (c16 & 1) * 8;
  int fb_n = t >> 1, fb_kh = (t & 1) * 32;

  f32x4 acc[4][4];
#pragma unroll
  for (int i = 0; i < 4; i++)
#pragma unroll
    for (int j = 0; j < 4; j++) acc[i][j] = (f32x4){0.f, 0.f, 0.f, 0.f};
  f32x4 va[8];

  auto loadA = [&](int kt) {
#pragma unroll
    for (int i = 0; i < 8; i++) va[i] = *(const f32x4*)(a + aoff[i] + kt * BK);
  };
  auto writeA = [&](int c) {
    char* db = (char*)lds_a2[c] + a_wbyte;
#pragma unroll
    for (int i = 0; i < 8; i++) {
      s16x4 v;
#pragma unroll
      for (int e = 0; e < 4; e++) v[e] = f2bf(va[i][e]);
      *(s16x4*)(db + i * 2048) = v;
    }
  };
  auto stageB = [&](int kt, int c) {
    const float* p = b + (size_t)g * KDIM * NDIM +
                     (size_t)(kt * BK + fb_kh) * NDIM + bn * BN + fb_n;
    float vals[32];
#pragma unroll
    for (int i = 0; i < 32; i++) vals[i] = p[(size_t)i * NDIM];
    char* lb = (char*)lds_b2[c] + fb_n * 128;
#pragma unroll
    for (int i8 = 0; i8 < 4; i8++) {
      int slot = (fb_kh >> 3) + i8;
      s16x8 v;
#pragma unroll
      for (int e = 0; e < 8; e++) v[e] = f2bf(vals[i8 * 8 + e]);
      *(s16x8*)(lb + ((slot ^ (fb_n & 7)) << 4)) = v;
    }
  };
  auto compute = [&](int c) {
#pragma unroll
    for (int ks = 0; ks < 2; ks++) {
      s16x8 af[4], bf[4];
#pragma unroll
      for (int fm = 0; fm < 4; fm++) {
        int row = wm * 64 + fm * 16 + lr;
        int slot = (ks * 4 + q) ^ (row & 7);
        af[fm] = *(const s16x8*)((const char*)lds_a2[c] + row * 128 + slot * 16);
      }
#pragma unroll
      for (int fn = 0; fn < 4; fn++) {
        int n = wn * 64 + fn * 16 + lr;
        int slot = (ks * 4 + q) ^ (n & 7);
        bf[fn] = *(const s16x8*)((const char*)lds_b2[c] + n * 128 + slot * 16);
      }
#pragma unroll
      for (int fm = 0; fm < 4; fm++)
#pragma unroll
        for (int fn = 0; fn < 4; fn++)
          acc[fm][fn] = __builtin_amdgcn_mfma_f32_16x16x32_bf16(
              af[fm], bf[fn], acc[fm][fn], 0, 0, 0);
    }
  };

  loadA(0);
  stageB(0, 0);
  writeA(0);
  __syncthreads();
  for (int kt = 0; kt < KTILES; kt++) {
    int cur = kt & 1, nxt = cur ^ 1;
    bool more = (kt + 1 < KTILES);
    if (more) loadA(kt + 1);
    compute(cur);
    if (more) {
      stageB(kt + 1, nxt);
      writeA(nxt);
      __syncthreads();
    }
  }
  size_t orow0 = (size_t)(off + m_loc);
#pragma unroll
  for (int fm = 0; fm < 4; fm++) {
#pragma unroll
    for (int j = 0; j < 4; j++) {
      int rm = wm * 64 + fm * 16 + q * 4 + j;
      if (rm < valid) {
        float* orow = out + (orow0 + rm) * NDIM + bn * BN + wn * 64 + lr;
#pragma unroll
        for (int fn = 0; fn < 4; fn++) orow[fn * 16] = acc[fm][fn][j];
      }
    }
  }
}

extern "C" void kernel_launch(void* const* d_in, const int* in_sizes, int n_in,
                              void* d_out, int out_size, void* d_ws,
                              size_t ws_size, hipStream_t stream) {
  const float* a = (const float*)d_in[0];
  const float* b = (const float*)d_in[1];
  const int* sizes = (const int*)d_in[2];
  const int* offs = (const int*)d_in[3];
  float* out = (float*)d_out;

  const size_t bt_bytes = (size_t)GCNT * KDIM * NDIM * 2;  // 64 MB
  if (ws_size >= bt_bytes) {
    bt_kernel<<<GCNT * 64, 256, 0, stream>>>(b, (char*)d_ws);
    gemm3<<<NBLK, 256, 0, stream>>>(a, (const char*)d_ws, sizes, offs, out);
  } else {
    gemm_fb<<<NBLK, 256, 0, stream>>>(a, b, sizes, offs, out);
  }
}